// Round 5
// baseline (133.443 us; speedup 1.0000x reference)
//
#include <hip/hip_runtime.h>
#include <math.h>

// ---------------------------------------------------------------------------
// B=32768 segments, E=1M sorted edges, DIM=64.
//   score[e] = dot(H[h[s]], R[rel[e]])        -> (h,rel) table, 3846x60
//   w        = segment_softmax(score)         (no-max: |dot| bounded -> f32 ok)
//   c_e      = tsum[tail[e]] - rsum[rel[e]]
//   out[s][:]= broadcast(sum w*c) = (sum exp*c)/(sum exp)
// Precompute P[i][r] = (exp(dot), exp(dot)*rsum[r]); per edge: 1 float2 gather
// + 1 float gather + 2 fma.
//
// SINGLE persistent kernel (launch overhead dominated at 2 launches):
//   phase A (grid-stride): P table (LDS-transposed R), seg_start scatter, tsum
//   software grid barrier (1024 blocks, co-residency guaranteed by resources:
//     __launch_bounds__(256,4) => VGPR<=128 => >=4 blk/CU; LDS 16.6KB => 9;
//     waves => 8; min=4 blk/CU * 256 CU = 1024 slots >= grid)
//   phase B (grid-stride): 32-lane group per segment, sum + shuffle reduce.
// ---------------------------------------------------------------------------

struct Params {
    const int* h; const int* eseg; const int* erel; const int* etail;
    const float* H; const float* R; const float* T;
    float2* P; float* tsum; int* seg_start; int* bar; float* out;
    int B, E, NH, NR, NT;
};

__global__ __launch_bounds__(256, 4) void fused_k(Params p)
{
    __shared__ float Rt[64 * 64];      // R transposed [d][r], NR<=64 (16 KB)
    __shared__ float rsum_s[64];

    const int tid   = threadIdx.x;
    const int nb    = gridDim.x;
    const int gsize = nb * 256;
    const int gtid  = blockIdx.x * 256 + tid;
    const int NR    = p.NR;

    // ---- A0: stage R transposed into LDS; rsum from LDS ----
    for (int t = tid; t < NR * 64; t += 256) {
        int r = t >> 6, d = t & 63;
        Rt[d * NR + r] = p.R[t];
    }
    __syncthreads();
    if (tid < NR) {
        float s = 0.f;
        #pragma unroll 8
        for (int d = 0; d < 64; ++d) s += Rt[d * NR + tid];
        rsum_s[tid] = s;
    }
    __syncthreads();

    // ---- A1: P[i*NR+r] = (exp(dot64(H[i],R[r])), exp*rsum[r]) ----
    for (int idx = gtid; idx < p.NH * NR; idx += gsize) {
        int i = idx / NR;
        int r = idx - i * NR;
        const float4* h4 = (const float4*)(p.H + (size_t)i * 64);
        float acc = 0.f;
        #pragma unroll
        for (int q = 0; q < 16; ++q) {
            float4 hv = h4[q];
            int d = q * 4;
            acc = fmaf(hv.x, Rt[(d + 0) * NR + r], acc);
            acc = fmaf(hv.y, Rt[(d + 1) * NR + r], acc);
            acc = fmaf(hv.z, Rt[(d + 2) * NR + r], acc);
            acc = fmaf(hv.w, Rt[(d + 3) * NR + r], acc);
        }
        float ex = __expf(acc);
        p.P[idx] = make_float2(ex, ex * rsum_s[r]);
    }

    // ---- A2: seg_start scatter from sorted eseg (prev via shuffle) ----
    for (int e = gtid; e < p.E; e += gsize) {
        int lane = tid & 63;
        int cur  = p.eseg[e];
        int prev = __shfl_up(cur, 1, 64);
        if (lane == 0) prev = (e == 0) ? -1 : p.eseg[e - 1];
        for (int s = prev + 1; s <= cur; ++s) p.seg_start[s] = e;
        if (e == p.E - 1)
            for (int s = cur + 1; s <= p.B; ++s) p.seg_start[s] = p.E;
    }

    // ---- A3: tsum rows (float4 + 16-lane reduce, 16 rows per block-iter) ----
    {
        int lane = tid & 63;
        int rq   = (tid >> 6) * 4 + (lane >> 4);      // 0..15 within block
        for (int base = blockIdx.x * 16; base < p.NT; base += nb * 16) {
            int row = base + rq;
            if (row < p.NT) {
                float4 v = ((const float4*)p.T)[(size_t)row * 16 + (lane & 15)];
                float s = v.x + v.y + v.z + v.w;
                s += __shfl_xor(s, 8, 64);
                s += __shfl_xor(s, 4, 64);
                s += __shfl_xor(s, 2, 64);
                s += __shfl_xor(s, 1, 64);
                if ((lane & 15) == 0) p.tsum[row] = s;
            }
        }
    }

    // ---- software grid barrier (all blocks co-resident by construction) ----
    __syncthreads();
    if (tid == 0) {
        __threadfence();   // release phase-A global writes device-wide
        __hip_atomic_fetch_add(p.bar, 1, __ATOMIC_ACQ_REL,
                               __HIP_MEMORY_SCOPE_AGENT);
        while (__hip_atomic_load(p.bar, __ATOMIC_ACQUIRE,
                                 __HIP_MEMORY_SCOPE_AGENT) < nb) {
            __builtin_amdgcn_s_sleep(1);
        }
    }
    __syncthreads();

    // ---- phase B: one 32-lane group per segment ----
    int sub = tid & 31;
    for (int grp = blockIdx.x * 8 + (tid >> 5); grp < p.B; grp += nb * 8) {
        int lo = p.seg_start[grp];
        int hi = p.seg_start[grp + 1];
        const float2* Prow = p.P + (size_t)p.h[grp] * NR;
        float se = 0.f, sec = 0.f;
        for (int e = lo + sub; e < hi; e += 32) {
            int rel = p.erel[e];
            int tl  = p.etail[e];
            float2 pv = Prow[rel];
            sec = fmaf(pv.x, p.tsum[tl], sec) - pv.y;
            se += pv.x;
        }
        #pragma unroll
        for (int off = 16; off; off >>= 1) {
            se  += __shfl_xor(se, off, 64);
            sec += __shfl_xor(sec, off, 64);
        }
        float vc = (se > 0.f) ? (sec / se) : 0.f;
        *(float2*)(p.out + (size_t)grp * 64 + sub * 2) = make_float2(vc, vc);
    }
}

extern "C" void kernel_launch(void* const* d_in, const int* in_sizes, int n_in,
                              void* d_out, int out_size, void* d_ws, size_t ws_size,
                              hipStream_t stream)
{
    Params prm;
    prm.h     = (const int*)d_in[0];
    prm.eseg  = (const int*)d_in[1];
    prm.erel  = (const int*)d_in[2];
    prm.etail = (const int*)d_in[3];
    prm.H     = (const float*)d_in[4];
    prm.R     = (const float*)d_in[5];
    prm.T     = (const float*)d_in[6];
    prm.B  = in_sizes[0];
    prm.E  = in_sizes[1];
    prm.NH = in_sizes[4] / 64;
    prm.NR = in_sizes[5] / 64;
    prm.NT = in_sizes[6] / 64;
    prm.out = (float*)d_out;

    // Workspace carve-out (256B aligned): P | tsum | seg_start | barrier (~2 MB)
    char*  ws  = (char*)d_ws;
    size_t off = 0;
    auto alloc = [&](size_t bytes) -> void* {
        void* q = ws + off;
        off = (off + bytes + 255) & ~(size_t)255;
        return q;
    };
    prm.P         = (float2*)alloc((size_t)prm.NH * prm.NR * sizeof(float2));
    prm.tsum      = (float*) alloc((size_t)prm.NT * sizeof(float));
    prm.seg_start = (int*)   alloc((size_t)(prm.B + 1) * sizeof(int));
    prm.bar       = (int*)   alloc(sizeof(int));
    (void)ws_size;

    hipMemsetAsync(prm.bar, 0, sizeof(int), stream);   // graph-capturable
    fused_k<<<1024, 256, 0, stream>>>(prm);
}

// Round 7
// 23.187 us; speedup vs baseline: 5.7552x; 5.7552x over previous
//
#include <hip/hip_runtime.h>
#include <hip/hip_fp16.h>
#include <math.h>

// ---------------------------------------------------------------------------
// B=32768 segments, E=1M sorted edges, DIM=64.
//   score[e] = dot(H[h[s]], R[rel[e]])        -> (h,rel) table, 3846x60
//   w        = segment_softmax(score)         (no-max: |dot|<~40 -> f32 exp ok;
//                                              max-subtraction cancels in ratio)
//   c_e      = tsum[tail[e]] - rsum[rel[e]]
//   out[s][:]= broadcast((sum exp*c)/(sum exp))
//
// Two plain launches (grid-wide sync abandoned: R3 launch-reject, R5 fabric
// contention, R6 nondeterministic stall).  Gather-footprint engineering:
//   P as f32 exp (920KB; 60-entry h-row = 2 lines -> L1-resident per block)
//   tsum as f16 (18.7KB -> L1-resident)   rsum (240B) staged in LDS.
// ---------------------------------------------------------------------------

__global__ __launch_bounds__(256) void setup_k(
    const int* __restrict__ seg, int E, int B, int* __restrict__ seg_start,
    const float* __restrict__ H, const float* __restrict__ R,
    const float* __restrict__ T,
    float* __restrict__ P, __half* __restrict__ tsum, float* __restrict__ rsumg,
    int NH, int NR, int NT, int eBlocks, int sBlocks)
{
    int b   = blockIdx.x;
    int tid = threadIdx.x;

    if (b < eBlocks) {
        // --- job0: seg_start scatter from sorted eseg (prev via shuffle) ---
        int e = b * 256 + tid;
        if (e < E) {
            int lane = tid & 63;
            int cur  = seg[e];
            int prev = __shfl_up(cur, 1, 64);
            if (lane == 0) prev = (e == 0) ? -1 : seg[e - 1];
            for (int s = prev + 1; s <= cur; ++s) seg_start[s] = e;
            if (e == E - 1)
                for (int s = cur + 1; s <= B; ++s) seg_start[s] = E;
        }
        return;
    }
    b -= eBlocks;

    if (b < sBlocks) {
        // --- job1: P[i*NR+r] = exp(dot64(H[i],R[r])), LDS-transposed R ---
        __shared__ float Rt[64 * 64];    // [d][r], NR<=64
        __shared__ float rsum_s[64];
        for (int t = tid; t < NR * 64; t += 256) {
            int r = t >> 6, d = t & 63;
            Rt[d * NR + r] = R[t];
        }
        __syncthreads();
        if (tid < NR) {
            float s = 0.f;
            #pragma unroll 8
            for (int d = 0; d < 64; ++d) s += Rt[d * NR + tid];
            rsum_s[tid] = s;
            if (b == 0) rsumg[tid] = s;          // publish once for main_k
        }
        __syncthreads();
        (void)rsum_s;

        int idx = b * 256 + tid;
        if (idx < NH * NR) {
            int i = idx / NR;
            int r = idx - i * NR;
            const float4* h4 = (const float4*)(H + (size_t)i * 64);
            float acc = 0.f;
            #pragma unroll
            for (int q = 0; q < 16; ++q) {
                float4 hv = h4[q];
                int d = q * 4;
                acc = fmaf(hv.x, Rt[(d + 0) * NR + r], acc);
                acc = fmaf(hv.y, Rt[(d + 1) * NR + r], acc);
                acc = fmaf(hv.z, Rt[(d + 2) * NR + r], acc);
                acc = fmaf(hv.w, Rt[(d + 3) * NR + r], acc);
            }
            P[idx] = __expf(acc);
        }
        return;
    }
    b -= sBlocks;

    // --- job2: tsum rows -> f16 (float4 + 16-lane reduce, 16 rows/block) ---
    {
        int lane = tid & 63;
        int row  = b * 16 + (tid >> 6) * 4 + (lane >> 4);
        if (row < NT) {
            float4 v = ((const float4*)T)[(size_t)row * 16 + (lane & 15)];
            float s = v.x + v.y + v.z + v.w;
            s += __shfl_xor(s, 8, 64);
            s += __shfl_xor(s, 4, 64);
            s += __shfl_xor(s, 2, 64);
            s += __shfl_xor(s, 1, 64);
            if ((lane & 15) == 0) tsum[row] = __float2half(s);
        }
    }
}

// One 32-lane group per segment (8 groups per 256-thread block).
__global__ __launch_bounds__(256) void main_k(
    const int* __restrict__ h,
    const int* __restrict__ edge_rel, const int* __restrict__ edge_tail,
    const float* __restrict__ P, const __half* __restrict__ tsum,
    const float* __restrict__ rsumg, const int* __restrict__ seg_start,
    float* __restrict__ out, int B, int NR)
{
    __shared__ float rsum_s[64];
    int tid = threadIdx.x;
    if (tid < NR) rsum_s[tid] = rsumg[tid];
    __syncthreads();

    int grp = blockIdx.x * 8 + (tid >> 5);
    int sub = tid & 31;
    if (grp >= B) return;

    int lo = seg_start[grp];
    int hi = seg_start[grp + 1];
    const float* Prow = P + (size_t)h[grp] * NR;

    float se = 0.f, sec = 0.f;
    for (int e = lo + sub; e < hi; e += 32) {
        int rel = edge_rel[e];
        int tl  = edge_tail[e];
        float pv = Prow[rel];
        float c  = __half2float(tsum[tl]) - rsum_s[rel];
        sec = fmaf(pv, c, sec);
        se += pv;
    }

    #pragma unroll
    for (int off = 16; off; off >>= 1) {
        se  += __shfl_xor(se, off, 64);
        sec += __shfl_xor(sec, off, 64);
    }

    float vc = (se > 0.f) ? (sec / se) : 0.f;
    *(float2*)(out + (size_t)grp * 64 + sub * 2) = make_float2(vc, vc);
}

extern "C" void kernel_launch(void* const* d_in, const int* in_sizes, int n_in,
                              void* d_out, int out_size, void* d_ws, size_t ws_size,
                              hipStream_t stream)
{
    const int*   h     = (const int*)d_in[0];
    const int*   eseg  = (const int*)d_in[1];
    const int*   erel  = (const int*)d_in[2];
    const int*   etail = (const int*)d_in[3];
    const float* Hv    = (const float*)d_in[4];
    const float* Rv    = (const float*)d_in[5];
    const float* Tv    = (const float*)d_in[6];

    int B  = in_sizes[0];
    int E  = in_sizes[1];
    int NH = in_sizes[4] / 64;
    int NR = in_sizes[5] / 64;
    int NT = in_sizes[6] / 64;

    // Workspace carve-out (256B aligned): P | tsum | rsum | seg_start (~1.2 MB)
    char*  ws  = (char*)d_ws;
    size_t off = 0;
    auto alloc = [&](size_t bytes) -> void* {
        void* q = ws + off;
        off = (off + bytes + 255) & ~(size_t)255;
        return q;
    };
    float*  P         = (float*) alloc((size_t)NH * NR * sizeof(float));
    __half* tsum      = (__half*)alloc((size_t)NT * sizeof(__half));
    float*  rsumg     = (float*) alloc(64 * sizeof(float));
    int*    seg_start = (int*)   alloc((size_t)(B + 1) * sizeof(int));
    (void)ws_size;

    int eBlocks = (E + 255) / 256;
    int sBlocks = (NH * NR + 255) / 256;
    int tBlocks = (NT + 15) / 16;
    setup_k<<<eBlocks + sBlocks + tBlocks, 256, 0, stream>>>(
        eseg, E, B, seg_start, Hv, Rv, Tv, P, tsum, rsumg, NH, NR, NT,
        eBlocks, sBlocks);

    main_k<<<(B + 7) / 8, 256, 0, stream>>>(
        h, erel, etail, P, tsum, rsumg, seg_start, (float*)d_out, B, NR);
}